// Round 6
// baseline (435.809 us; speedup 1.0000x reference)
//
#include <hip/hip_runtime.h>

typedef unsigned short u16;
typedef __attribute__((ext_vector_type(8))) short bf16x8;
typedef __attribute__((ext_vector_type(4))) short s16x4;
typedef __attribute__((ext_vector_type(4))) float f32x4;

__device__ __forceinline__ float bf2f(u16 u) {
  union { unsigned u; float f; } c; c.u = ((unsigned)u) << 16; return c.f;
}
__device__ __forceinline__ u16 f2bf(float f) {
  union { float f; unsigned u; } c; c.f = f;
  return (u16)((c.u + 0x7fffu + ((c.u >> 16) & 1u)) >> 16);
}
#if __has_builtin(__builtin_amdgcn_cvt_pk_bf16_f32)
__device__ __forceinline__ unsigned pkbf(float a, float b) {
  auto v = __builtin_amdgcn_cvt_pk_bf16_f32(a, b);
  return __builtin_bit_cast(unsigned, v);
}
#else
__device__ __forceinline__ unsigned pkbf(float a, float b) {
  return (unsigned)f2bf(a) | ((unsigned)f2bf(b) << 16);
}
#endif
#if __has_builtin(__builtin_amdgcn_mfma_f32_16x16x16bf16_1k)
#define MFMA16(a, b, c) __builtin_amdgcn_mfma_f32_16x16x16bf16_1k(a, b, c, 0, 0, 0)
#define HAVE_MFMA16 1
#endif
#if __has_builtin(__builtin_amdgcn_permlane16_swap) && \
    __has_builtin(__builtin_amdgcn_permlane32_swap)
#define HAVE_PLSWAP 1
__device__ __forceinline__ void plswap32(unsigned& a, unsigned& b) {
  auto r = __builtin_amdgcn_permlane32_swap(a, b, false, false);
  a = r[0]; b = r[1];
}
__device__ __forceinline__ void plswap16(unsigned& a, unsigned& b) {
  auto r = __builtin_amdgcn_permlane16_swap(a, b, false, false);
  a = r[0]; b = r[1];
}
#endif
// raw exp2 (v_exp_f32); Q pre-scaled by log2e/sqrt(128) so p = e^(qk/sqrt128)
#if __has_builtin(__builtin_amdgcn_exp2f)
#define EXP2(x) __builtin_amdgcn_exp2f(x)
#else
#define EXP2(x) __expf((x) * 0.69314718f)
#endif
__device__ __forceinline__ void gl2lds16(const u16* g, u16* l) {
  __builtin_amdgcn_global_load_lds(
      (const __attribute__((address_space(1))) void*)g,
      (__attribute__((address_space(3))) void*)l, 16, 0, 0);
}

// ---------------------------------------------------------------------------
// transpose_cast tile body: f32 in [.][ldin] -> bf16 out [.][ldout], 64x64.
// ---------------------------------------------------------------------------
__device__ __forceinline__ void tr_cast_tile(const float* __restrict__ in,
                                             u16* __restrict__ out,
                                             int ldin, int ldout, int bx, int by) {
  __shared__ u16 tile[64][66];
  const int tx = threadIdx.x;
  const int lr = tx & 31, lc = tx >> 5;
  const int r0 = by << 6, c0 = bx << 6;
#pragma unroll
  for (int i = 0; i < 8; ++i) {
    int r = lc + (i << 3);
    float2 v = *(const float2*)&in[(size_t)(r0 + r) * ldin + c0 + (lr << 1)];
    *(unsigned*)&tile[r][lr << 1] = pkbf(v.x, v.y);
  }
  __syncthreads();
#pragma unroll
  for (int i = 0; i < 8; ++i) {
    int c = lc + (i << 3);
    unsigned v = (unsigned)tile[lr << 1][c] | ((unsigned)tile[(lr << 1) + 1][c] << 16);
    *(unsigned*)&out[(size_t)(c0 + c) * ldout + r0 + (lr << 1)] = v;
  }
}

// ---------------------------------------------------------------------------
// prep: x cast (blocks 0..2047) + WqT (2048..4095) + WkT (4096..4607) +
// WvT (4608..5119).
// ---------------------------------------------------------------------------
__global__ __launch_bounds__(256) void prep(const float* __restrict__ x,
                                            u16* __restrict__ xb,
                                            const float* __restrict__ Wq,
                                            u16* __restrict__ WqT,
                                            const float* __restrict__ Wk,
                                            u16* __restrict__ WkT,
                                            const float* __restrict__ Wv,
                                            u16* __restrict__ WvT) {
  int b = blockIdx.x;
  if (b < 2048) {
    int i = (b * 256 + threadIdx.x) * 8;
    float4 a = *(const float4*)&x[i];
    float4 c = *(const float4*)&x[i + 4];
    union { unsigned u[4]; bf16x8 v; } w;
    w.u[0] = pkbf(a.x, a.y); w.u[1] = pkbf(a.z, a.w);
    w.u[2] = pkbf(c.x, c.y); w.u[3] = pkbf(c.z, c.w);
    *(bf16x8*)&xb[i] = w.v;
  } else if (b < 4096) {
    int t = b - 2048;
    tr_cast_tile(Wq, WqT, 4096, 2048, t & 63, t >> 6);
  } else if (b < 4608) {
    int t = b - 4096;
    tr_cast_tile(Wk, WkT, 1024, 2048, t & 15, t >> 4);
  } else {
    int t = b - 4608;
    tr_cast_tile(Wv, WvT, 1024, 2048, t & 15, t >> 4);
  }
}

__global__ __launch_bounds__(256) void transpose_cast(const float* __restrict__ in,
                                                      u16* __restrict__ out,
                                                      int ldin, int ldout) {
  tr_cast_tile(in, out, ldin, ldout, blockIdx.x, blockIdx.y);
}

// ---------------------------------------------------------------------------
// BK=64 GEMM: C[M,N] = A[M,K] @ BT[N,K]^T. 128x128 tile, m97 LDS pattern,
// bf16 out. R13: bijective XCD remap (768 = 8 XCDs x 96): each XCD owns 2
// consecutive m-rows so its 96 blocks share 2 A-panels in L2 (T1).
// ---------------------------------------------------------------------------
__global__ __launch_bounds__(256) void gemm_bt(const u16* __restrict__ A,
                                               const u16* __restrict__ BT,
                                               u16* __restrict__ C,
                                               int M, int N, int K) {
  __shared__ u16 Asl[2][128 * 32];
  __shared__ u16 Bsl[2][128 * 32];
  const int tid = threadIdx.x;
  const int lane = tid & 63, wv = tid >> 6;
  const int lr = lane & 15, qd = lane >> 4;
  const int wr = wv >> 1, wc = wv & 1;
  const int id = blockIdx.y * 48 + blockIdx.x;      // 768 blocks
  const int swz = (id & 7) * 96 + (id >> 3);        // bijective (768 = 8*96)
  const int m0 = (swz / 48) << 7, n0 = (swz % 48) << 7;
  const int srow = lane >> 2, scol = (lane & 3) << 3;
  const u16* Ag = &A[(size_t)(m0 + wv * 32 + srow) * K + scol];
  const u16* Bg = &BT[(size_t)(n0 + wv * 32 + srow) * K + scol];
  const size_t rstr16 = (size_t)16 * K;
  f32x4 acc[4][4] = {};
  for (int k0 = 0; k0 < K; k0 += 64) {
    __syncthreads();
#pragma unroll
    for (int p = 0; p < 2; ++p) {
#pragma unroll
      for (int hh = 0; hh < 2; ++hh) {
        gl2lds16(Ag + k0 + p * 32 + hh * rstr16, &Asl[p][wv * 1024 + hh * 512]);
        gl2lds16(Bg + k0 + p * 32 + hh * rstr16, &Bsl[p][wv * 1024 + hh * 512]);
      }
    }
    __syncthreads();
#pragma unroll
    for (int p = 0; p < 2; ++p) {
      bf16x8 af[4], bfr[4];
#pragma unroll
      for (int i = 0; i < 4; ++i) {
        af[i]  = *(const bf16x8*)&Asl[p][(wr * 64 + i * 16 + lr) * 32 + qd * 8];
        bfr[i] = *(const bf16x8*)&Bsl[p][(wc * 64 + i * 16 + lr) * 32 + qd * 8];
      }
#pragma unroll
      for (int mi = 0; mi < 4; ++mi)
#pragma unroll
        for (int ni = 0; ni < 4; ++ni)
          acc[mi][ni] = __builtin_amdgcn_mfma_f32_16x16x32_bf16(
              af[mi], bfr[ni], acc[mi][ni], 0, 0, 0);
    }
  }
#pragma unroll
  for (int mi = 0; mi < 4; ++mi)
#pragma unroll
    for (int ni = 0; ni < 4; ++ni)
#pragma unroll
      for (int r = 0; r < 4; ++r)
        C[(size_t)(m0 + wr * 64 + mi * 16 + qd * 4 + r) * N +
          n0 + wc * 64 + ni * 16 + lr] = f2bf(acc[mi][ni][r]);
}

// ---------------------------------------------------------------------------
// BK=64 split-K GEMM (out-proj): f32 += via unsafeAtomicAdd; C pre-zeroed.
// R13: bijective XCD remap within each z (256 = 8 x 32).
// ---------------------------------------------------------------------------
__global__ __launch_bounds__(256) void gemm_bt_sk(const u16* __restrict__ A,
                                                  const u16* __restrict__ BT,
                                                  float* __restrict__ C,
                                                  int M, int N, int K, int kspan) {
  __shared__ u16 Asl[2][128 * 32];
  __shared__ u16 Bsl[2][128 * 32];
  const int tid = threadIdx.x;
  const int lane = tid & 63, wv = tid >> 6;
  const int lr = lane & 15, qd = lane >> 4;
  const int wr = wv >> 1, wc = wv & 1;
  const int id = blockIdx.y * 16 + blockIdx.x;      // 256 blocks per z
  const int swz = (id & 7) * 32 + (id >> 3);        // bijective (256 = 8*32)
  const int m0 = (swz >> 4) << 7, n0 = (swz & 15) << 7;
  const int kbeg = blockIdx.z * kspan;
  const int srow = lane >> 2, scol = (lane & 3) << 3;
  const u16* Ag = &A[(size_t)(m0 + wv * 32 + srow) * K + kbeg + scol];
  const u16* Bg = &BT[(size_t)(n0 + wv * 32 + srow) * K + kbeg + scol];
  const size_t rstr16 = (size_t)16 * K;
  f32x4 acc[4][4] = {};
  for (int k0 = 0; k0 < kspan; k0 += 64) {
    __syncthreads();
#pragma unroll
    for (int p = 0; p < 2; ++p) {
#pragma unroll
      for (int hh = 0; hh < 2; ++hh) {
        gl2lds16(Ag + k0 + p * 32 + hh * rstr16, &Asl[p][wv * 1024 + hh * 512]);
        gl2lds16(Bg + k0 + p * 32 + hh * rstr16, &Bsl[p][wv * 1024 + hh * 512]);
      }
    }
    __syncthreads();
#pragma unroll
    for (int p = 0; p < 2; ++p) {
      bf16x8 af[4], bfr[4];
#pragma unroll
      for (int i = 0; i < 4; ++i) {
        af[i]  = *(const bf16x8*)&Asl[p][(wr * 64 + i * 16 + lr) * 32 + qd * 8];
        bfr[i] = *(const bf16x8*)&Bsl[p][(wc * 64 + i * 16 + lr) * 32 + qd * 8];
      }
#pragma unroll
      for (int mi = 0; mi < 4; ++mi)
#pragma unroll
        for (int ni = 0; ni < 4; ++ni)
          acc[mi][ni] = __builtin_amdgcn_mfma_f32_16x16x32_bf16(
              af[mi], bfr[ni], acc[mi][ni], 0, 0, 0);
    }
  }
#pragma unroll
  for (int mi = 0; mi < 4; ++mi)
#pragma unroll
    for (int ni = 0; ni < 4; ++ni)
#pragma unroll
      for (int r = 0; r < 4; ++r)
        unsafeAtomicAdd(&C[(size_t)(m0 + wr * 64 + mi * 16 + qd * 4 + r) * N +
                           n0 + wc * 64 + ni * 16 + lr], acc[mi][ni][r]);
}

// ---------------------------------------------------------------------------
// norm_vt: blocks 0..2047 = fused RMSNorm+RoPE on QKV [2048][6144];
// blocks 2048..2559 = V transpose. Q scaled by log2e/sqrt(128) (exp2 fold).
// ---------------------------------------------------------------------------
__global__ __launch_bounds__(256) void norm_vt(u16* __restrict__ QKV,
                                               u16* __restrict__ VTb,
                                               const float* __restrict__ qw,
                                               const float* __restrict__ kw,
                                               const float* __restrict__ sinb,
                                               const float* __restrict__ cosb) {
  int b = blockIdx.x;
  if (b >= 2048) {
    __shared__ u16 tile[64][66];
    int t = b - 2048;
    const int tx = threadIdx.x;
    const int lr = tx & 31, lc = tx >> 5;
    const int r0 = (t >> 4) << 6, c0 = (t & 15) << 6;
    const u16* in = QKV + 5120;
#pragma unroll
    for (int i = 0; i < 8; ++i) {
      int r = lc + (i << 3);
      unsigned v = *(const unsigned*)&in[(size_t)(r0 + r) * 6144 + c0 + (lr << 1)];
      *(unsigned*)&tile[r][lr << 1] = v;
    }
    __syncthreads();
#pragma unroll
    for (int i = 0; i < 8; ++i) {
      int c = lc + (i << 3);
      unsigned v = (unsigned)tile[lr << 1][c] | ((unsigned)tile[(lr << 1) + 1][c] << 16);
      *(unsigned*)&VTb[(size_t)(c0 + c) * 2048 + r0 + (lr << 1)] = v;
    }
    return;
  }
  const int t = b;
  const int wv = threadIdx.x >> 6, l = threadIdx.x & 63;
  const float sv = sinb[t * 64 + l];
  const float cv = cosb[t * 64 + l];
  const float qscale = 0.12753102543f;  // log2(e)/sqrt(128)
  u16* Q = QKV + (size_t)t * 6144;
  u16* Kb = Q + 4096;
  for (int j = wv; j < 16; j += 4) {
    u16* base = Q + j * 256;
    float x0 = bf2f(base[2 * l]);
    float x1 = bf2f(base[2 * l + 1]);
    float x2 = bf2f(base[128 + 2 * l]);
    float x3 = bf2f(base[129 + 2 * l]);
    float ss = x0 * x0 + x1 * x1 + x2 * x2 + x3 * x3;
#pragma unroll
    for (int m = 1; m < 64; m <<= 1) ss += __shfl_xor(ss, m, 64);
    float rn = rsqrtf(ss * (1.0f / 256.0f) + 1e-6f);
    float w0 = qw[2 * l], w1 = qw[2 * l + 1];
    float w2 = qw[128 + 2 * l], w3 = qw[129 + 2 * l];
    x0 *= rn * w0; x1 *= rn * w1; x2 *= rn * w2; x3 *= rn * w3;
    base[l]       = f2bf((x0 * cv - x1 * sv) * qscale);
    base[64 + l]  = f2bf((x0 * sv + x1 * cv) * qscale);
    base[128 + l] = f2bf((x2 * cv - x3 * sv) * qscale);
    base[192 + l] = f2bf((x2 * sv + x3 * cv) * qscale);
  }
  for (int j = wv; j < 8; j += 4) {
    u16* base = Kb + j * 128;
    float x0 = bf2f(base[2 * l]);
    float x1 = bf2f(base[2 * l + 1]);
    float ss = x0 * x0 + x1 * x1;
#pragma unroll
    for (int m = 1; m < 64; m <<= 1) ss += __shfl_xor(ss, m, 64);
    float rn = rsqrtf(ss * (1.0f / 128.0f) + 1e-6f);
    float w0 = kw[2 * l], w1 = kw[2 * l + 1];
    x0 *= rn * w0; x1 *= rn * w1;
    base[l]      = f2bf(x0 * cv - x1 * sv);
    base[64 + l] = f2bf(x0 * sv + x1 * cv);
  }
}

// ---------------------------------------------------------------------------
// Flash attention, S^T form, NO online max, p=exp2(s). R13:
// - K staged in LDS (dbuf, one barrier per tile) as before.
// - V read DIRECTLY from global (L2-resident 512KB panel per kv, XCD-grouped)
//   in the PV loop — m169 precedent: drop staging for L2-fitting data.
//   Removes half the staging + vmcnt drain volume + all V bank conflicts.
//   LDS 64KB -> 32KB.
// ---------------------------------------------------------------------------
__global__ __launch_bounds__(256, 2) void flash(const u16* __restrict__ QKV,
                                                const u16* __restrict__ VTb,
                                                u16* __restrict__ O,
                                                float* __restrict__ L) {
  __shared__ u16 Ks0[64 * 128];   // [key][d], swizzled
  __shared__ u16 Ks1[64 * 128];
  const int tid = threadIdx.x;
  const int wv = tid >> 6, lane = tid & 63;
  const int c = lane & 15, qd = lane >> 4;
  // wgid = r8 + 8*(qx + 16*hh); h = r8 + 8*hh  (bijective; h%8 == wgid%8)
  const int wgid = blockIdx.x;
  const int r8 = wgid & 7, t_ = wgid >> 3;
  const int qx = t_ & 15, hh = t_ >> 4;
  const int h = r8 + (hh << 3);
  const int kv = h >> 2;
  const int qb = (qx << 7) + wv * 32;
  const int cx = c & 7;
  const int krow_off = lane >> 4;
  const int kpb = lane & 15;
  const u16* Vg = &VTb[(size_t)(kv * 128) * 2048];  // V^T panel [128 d][2048 keys]
  bf16x8 qf[2][4];
#pragma unroll
  for (int ms = 0; ms < 2; ++ms)
#pragma unroll
    for (int ks = 0; ks < 4; ++ks)
      qf[ms][ks] = *(const bf16x8*)&QKV[(size_t)(qb + ms * 16 + c) * 6144 +
                                        h * 128 + ks * 32 + qd * 8];
  f32x4 o[2][8] = {};
  float lrun[2] = {0.f, 0.f};

  auto stage = [&](int k0, u16* Kd) {
#pragma unroll
    for (int it = 0; it < 4; ++it) {
      int rbase = (wv * 4 + it) * 4;
      int r = rbase + krow_off;
      int klb = kpb ^ (r & 7);
      gl2lds16(&QKV[(size_t)(k0 + r) * 6144 + 4096 + kv * 128 + klb * 8],
               &Kd[rbase * 128]);
    }
  };

  auto compute = [&](const u16* Ks, int k0v) {
    f32x4 s[2][4];
    __builtin_amdgcn_s_setprio(1);
#pragma unroll
    for (int ns = 0; ns < 4; ++ns) {
      f32x4 a0 = {0.f, 0.f, 0.f, 0.f}, a1 = {0.f, 0.f, 0.f, 0.f};
#pragma unroll
      for (int ks = 0; ks < 4; ++ks) {
        bf16x8 kf = *(const bf16x8*)
            &Ks[(ns * 16 + c) * 128 + (((4 * ks + qd) ^ cx) << 3)];
        a0 = __builtin_amdgcn_mfma_f32_16x16x32_bf16(kf, qf[0][ks], a0, 0, 0, 0);
        a1 = __builtin_amdgcn_mfma_f32_16x16x32_bf16(kf, qf[1][ks], a1, 0, 0, 0);
      }
      s[0][ns] = a0; s[1][ns] = a1;
    }
    __builtin_amdgcn_s_setprio(0);
#pragma unroll
    for (int ms = 0; ms < 2; ++ms) {
      float rs = 0.f;
#pragma unroll
      for (int ns = 0; ns < 4; ++ns)
#pragma unroll
        for (int r = 0; r < 4; ++r) {
          float p = EXP2(s[ms][ns][r]);
          s[ms][ns][r] = p; rs += p;
        }
      lrun[ms] += rs;
    }
#ifdef HAVE_PLSWAP
    // PV on 16x16x32: lane must hold 8 consecutive keys of P (B-operand
    // k-group qd). S^T fragments give 4 keys per lane-group; the exchange
    // (b0,b2)=pl16(pl32(p0,p2)), (b1,b3)=pl16(pl32(p1,p3)) produces exactly
    // the dwords [keys 8qd+2d, 8qd+2d+1] per lane.
#pragma unroll
    for (int t2 = 0; t2 < 2; ++t2) {
      bf16x8 pB[2];
#pragma unroll
      for (int ms = 0; ms < 2; ++ms) {
        unsigned p0 = pkbf(s[ms][2 * t2][0],     s[ms][2 * t2][1]);
        unsigned p1 = pkbf(s[ms][2 * t2][2],     s[ms][2 * t2][3]);
        unsigned p2 = pkbf(s[ms][2 * t2 + 1][0], s[ms][2 * t2 + 1][1]);
        unsigned p3 = pkbf(s[ms][2 * t2 + 1][2], s[ms][2 * t2 + 1][3]);
        plswap32(p0, p2); plswap16(p0, p2);  // -> b0, b2
        plswap32(p1, p3); plswap16(p1, p3);  // -> b1, b3
        union { unsigned u[4]; bf16x8 v; } bb;
        bb.u[0] = p0; bb.u[1] = p1; bb.u[2] = p2; bb.u[3] = p3;
        pB[ms] = bb.v;
      }
      __builtin_amdgcn_s_setprio(1);
#pragma unroll
      for (int n8 = 0; n8 < 8; ++n8) {
        bf16x8 vf = *(const bf16x8*)
            &Vg[(size_t)(n8 * 16 + c) * 2048 + k0v + (4 * t2 + qd) * 8];
        o[0][n8] = __builtin_amdgcn_mfma_f32_16x16x32_bf16(vf, pB[0], o[0][n8], 0, 0, 0);
        o[1][n8] = __builtin_amdgcn_mfma_f32_16x16x32_bf16(vf, pB[1], o[1][n8], 0, 0, 0);
      }
      __builtin_amdgcn_s_setprio(0);
    }
#elif defined(HAVE_MFMA16)
#pragma unroll
    for (int ns = 0; ns < 4; ++ns) {
      s16x4 pb[2];
#pragma unroll
      for (int ms = 0; ms < 2; ++ms) {
        union { unsigned u[2]; s16x4 v; } pu;
        pu.u[0] = pkbf(s[ms][ns][0], s[ms][ns][1]);
        pu.u[1] = pkbf(s[ms][ns][2], s[ms][ns][3]);
        pb[ms] = pu.v;
      }
#pragma unroll
      for (int n8 = 0; n8 < 8; ++n8) {
        s16x4 vf = *(const s16x4*)
            &Vg[(size_t)(n8 * 16 + c) * 2048 + k0v +
                ((2 * ns) + (qd >> 1)) * 8 + (qd & 1) * 4];
        o[0][n8] = MFMA16(vf, pb[0], o[0][n8]);
        o[1][n8] = MFMA16(vf, pb[1], o[1][n8]);
      }
    }
#else
    unsigned pk[2][4][2];
#pragma unroll
    for (int ms = 0; ms < 2; ++ms)
#pragma unroll
      for (int ns = 0; ns < 4; ++ns) {
        pk[ms][ns][0] = pkbf(s[ms][ns][0], s[ms][ns][1]);
        pk[ms][ns][1] = pkbf(s[ms][ns][2], s[ms][ns][3]);
      }
    const bool hi = lane >= 32;
    const int sl0 = ((lane >> 4) & 1) * 32 + c;
    const int sl1 = sl0 + 16;
#pragma unroll
    for (int t2 = 0; t2 < 2; ++t2) {
      union { int i[4]; bf16x8 v; } pb[2];
#pragma unroll
      for (int ms = 0; ms < 2; ++ms)
#pragma unroll
        for (int dw = 0; dw < 4; ++dw) {
          int rg = dw & 1;
          int sl = dw < 2 ? sl0 : sl1;
          int va = __shfl((int)pk[ms][2 * t2][rg], sl, 64);
          int vb = __shfl((int)pk[ms][2 * t2 + 1][rg], sl, 64);
          pb[ms].i[dw] = hi ? vb : va;
        }
#pragma unroll
      for (int n8 = 0; n8 < 8; ++n8) {
        bf16x8 vf = *(const bf16x8*)
            &Vg[(size_t)(n8 * 16 + c) * 2048 + k0v + (4 * t2 + qd) * 8];
        o[0][n8] = __builtin_amdgcn_mfma_f32_16x16x32_bf16(vf, pb[0].v, o[0][n8], 0, 0, 0);
        o[1][n8] = __builtin_amdgcn_mfma_f32_16x16x32_bf16(vf, pb[1].v, o[1][n8], 0, 0, 0);
      }
    }
#endif
  };

  stage(0, Ks0);
#pragma unroll 1
  for (int k0 = 0; k0 < 2048; k0 += 128) {
    __syncthreads();             // drains stage->Ks0; all waves done with Ks1
    stage(k0 + 64, Ks1);         // prefetch next tile; latency hides under compute
    compute(Ks0, k0);
    __syncthreads();             // drains stage->Ks1; all waves done with Ks0
    if (k0 + 128 < 2048) stage(k0 + 128, Ks0);
    compute(Ks1, k0 + 64);
  }
#pragma unroll
  for (int ms = 0; ms < 2; ++ms) {
    lrun[ms] += __shfl_xor(lrun[ms], 16, 64);
    lrun[ms] += __shfl_xor(lrun[ms], 32, 64);
  }
  if (qd == 0) {
    L[(qb + c) * 32 + h] = lrun[0];
    L[(qb + 16 + c) * 32 + h] = lrun[1];
  }
#pragma unroll
  for (int ms = 0; ms < 2; ++ms)
#pragma unroll
    for (int n8 = 0; n8 < 8; ++n8) {
      union { unsigned u[2]; s16x4 v; } w;
      w.u[0] = pkbf(o[ms][n8][0], o[ms][n8][1]);
      w.u[1] = pkbf(o[ms][n8][2], o[ms][n8][3]);
      *(s16x4*)&O[(size_t)(qb + ms * 16 + c) * 4096 + h * 128 + n8 * 16 + qd * 4] = w.v;
    }
}

// ---------------------------------------------------------------------------
// combine: O <- O / L, elementwise over [2048][32][128] (pure normalize).
// ---------------------------------------------------------------------------
__global__ __launch_bounds__(256) void combine(u16* __restrict__ O,
                                               const float* __restrict__ L) {
  int i8 = (blockIdx.x * 256 + threadIdx.x) * 8;
  int q = i8 >> 12, h = (i8 >> 7) & 31;
  float inv = 1.0f / L[q * 32 + h];
  bf16x8 a = *(bf16x8*)&O[i8];
  union { unsigned u[4]; bf16x8 v; } w;
#pragma unroll
  for (int j = 0; j < 4; ++j) {
    float e0 = bf2f((u16)a[2 * j]) * inv;
    float e1 = bf2f((u16)a[2 * j + 1]) * inv;
    w.u[j] = pkbf(e0, e1);
  }
  *(bf16x8*)&O[i8] = w.v;
}

// ---------------------------------------------------------------------------
extern "C" void kernel_launch(void* const* d_in, const int* in_sizes, int n_in,
                              void* d_out, int out_size, void* d_ws, size_t ws_size,
                              hipStream_t stream) {
  const float* x    = (const float*)d_in[0];
  const float* Wq   = (const float*)d_in[1];
  const float* Wk   = (const float*)d_in[2];
  const float* Wv   = (const float*)d_in[3];
  const float* Wo   = (const float*)d_in[4];
  const float* qnw  = (const float*)d_in[5];
  const float* knw  = (const float*)d_in[6];
  const float* sinb = (const float*)d_in[7];
  const float* cosb = (const float*)d_in[8];
  float* out = (float*)d_out;
  char* ws = (char*)d_ws;
  const size_t MB = 1024 * 1024;
  u16* WqkvT = (u16*)(ws + 0 * MB);
  u16* Op0   = (u16*)(ws + 0 * MB);
  float* L0f = (float*)(ws + 16 * MB);
  u16* QKV = (u16*)(ws + 24 * MB);
  u16* WoT = (u16*)(ws + 24 * MB);
  u16* xb  = (u16*)(ws + 48 * MB);
  u16* VTb = (u16*)(ws + 64 * MB);

  prep<<<5120, 256, 0, stream>>>(x, xb, Wq, WqkvT,
                                 Wk, WqkvT + (size_t)4096 * 2048,
                                 Wv, WqkvT + (size_t)5120 * 2048);
  gemm_bt<<<dim3(48, 16), 256, 0, stream>>>(xb, WqkvT, QKV, 2048, 6144, 2048);
  norm_vt<<<2560, 256, 0, stream>>>(QKV, VTb, qnw, knw, sinb, cosb);
  flash<<<512, 256, 0, stream>>>(QKV, VTb, Op0, L0f);
  transpose_cast<<<dim3(32, 64), 256, 0, stream>>>(Wo, WoT, 2048, 4096);
  combine<<<4096, 256, 0, stream>>>(Op0, L0f);
  hipMemsetAsync(out, 0, (size_t)2048 * 2048 * 4, stream);
  gemm_bt_sk<<<dim3(16, 16, 2), 256, 0, stream>>>(Op0, WoT, out, 2048, 2048, 4096, 2048);
  (void)in_sizes; (void)n_in; (void)out_size; (void)ws_size;
}

// Round 7
// 389.919 us; speedup vs baseline: 1.1177x; 1.1177x over previous
//
#include <hip/hip_runtime.h>

typedef unsigned short u16;
typedef __attribute__((ext_vector_type(8))) short bf16x8;
typedef __attribute__((ext_vector_type(4))) short s16x4;
typedef __attribute__((ext_vector_type(4))) float f32x4;

__device__ __forceinline__ float bf2f(u16 u) {
  union { unsigned u; float f; } c; c.u = ((unsigned)u) << 16; return c.f;
}
__device__ __forceinline__ u16 f2bf(float f) {
  union { float f; unsigned u; } c; c.f = f;
  return (u16)((c.u + 0x7fffu + ((c.u >> 16) & 1u)) >> 16);
}
#if __has_builtin(__builtin_amdgcn_cvt_pk_bf16_f32)
__device__ __forceinline__ unsigned pkbf(float a, float b) {
  auto v = __builtin_amdgcn_cvt_pk_bf16_f32(a, b);
  return __builtin_bit_cast(unsigned, v);
}
#else
__device__ __forceinline__ unsigned pkbf(float a, float b) {
  return (unsigned)f2bf(a) | ((unsigned)f2bf(b) << 16);
}
#endif
#if __has_builtin(__builtin_amdgcn_mfma_f32_16x16x16bf16_1k)
#define MFMA16(a, b, c) __builtin_amdgcn_mfma_f32_16x16x16bf16_1k(a, b, c, 0, 0, 0)
#define HAVE_MFMA16 1
#endif
#if __has_builtin(__builtin_amdgcn_permlane16_swap) && \
    __has_builtin(__builtin_amdgcn_permlane32_swap)
#define HAVE_PLSWAP 1
__device__ __forceinline__ void plswap32(unsigned& a, unsigned& b) {
  auto r = __builtin_amdgcn_permlane32_swap(a, b, false, false);
  a = r[0]; b = r[1];
}
__device__ __forceinline__ void plswap16(unsigned& a, unsigned& b) {
  auto r = __builtin_amdgcn_permlane16_swap(a, b, false, false);
  a = r[0]; b = r[1];
}
#endif
// raw exp2 (v_exp_f32); Q pre-scaled by log2e/sqrt(128) so p = e^(qk/sqrt128)
#if __has_builtin(__builtin_amdgcn_exp2f)
#define EXP2(x) __builtin_amdgcn_exp2f(x)
#else
#define EXP2(x) __expf((x) * 0.69314718f)
#endif
__device__ __forceinline__ void gl2lds16(const u16* g, u16* l) {
  __builtin_amdgcn_global_load_lds(
      (const __attribute__((address_space(1))) void*)g,
      (__attribute__((address_space(3))) void*)l, 16, 0, 0);
}

// ---------------------------------------------------------------------------
// transpose_cast tile body: f32 in [.][ldin] -> bf16 out [.][ldout], 64x64.
// ---------------------------------------------------------------------------
__device__ __forceinline__ void tr_cast_tile(const float* __restrict__ in,
                                             u16* __restrict__ out,
                                             int ldin, int ldout, int bx, int by) {
  __shared__ u16 tile[64][66];
  const int tx = threadIdx.x;
  const int lr = tx & 31, lc = tx >> 5;
  const int r0 = by << 6, c0 = bx << 6;
#pragma unroll
  for (int i = 0; i < 8; ++i) {
    int r = lc + (i << 3);
    float2 v = *(const float2*)&in[(size_t)(r0 + r) * ldin + c0 + (lr << 1)];
    *(unsigned*)&tile[r][lr << 1] = pkbf(v.x, v.y);
  }
  __syncthreads();
#pragma unroll
  for (int i = 0; i < 8; ++i) {
    int c = lc + (i << 3);
    unsigned v = (unsigned)tile[lr << 1][c] | ((unsigned)tile[(lr << 1) + 1][c] << 16);
    *(unsigned*)&out[(size_t)(c0 + c) * ldout + r0 + (lr << 1)] = v;
  }
}

// ---------------------------------------------------------------------------
// prep: x cast (blocks 0..2047) + WqT (2048..4095) + WkT (4096..4607) +
// WvT (4608..5119).
// ---------------------------------------------------------------------------
__global__ __launch_bounds__(256) void prep(const float* __restrict__ x,
                                            u16* __restrict__ xb,
                                            const float* __restrict__ Wq,
                                            u16* __restrict__ WqT,
                                            const float* __restrict__ Wk,
                                            u16* __restrict__ WkT,
                                            const float* __restrict__ Wv,
                                            u16* __restrict__ WvT) {
  int b = blockIdx.x;
  if (b < 2048) {
    int i = (b * 256 + threadIdx.x) * 8;
    float4 a = *(const float4*)&x[i];
    float4 c = *(const float4*)&x[i + 4];
    union { unsigned u[4]; bf16x8 v; } w;
    w.u[0] = pkbf(a.x, a.y); w.u[1] = pkbf(a.z, a.w);
    w.u[2] = pkbf(c.x, c.y); w.u[3] = pkbf(c.z, c.w);
    *(bf16x8*)&xb[i] = w.v;
  } else if (b < 4096) {
    int t = b - 2048;
    tr_cast_tile(Wq, WqT, 4096, 2048, t & 63, t >> 6);
  } else if (b < 4608) {
    int t = b - 4096;
    tr_cast_tile(Wk, WkT, 1024, 2048, t & 15, t >> 4);
  } else {
    int t = b - 4608;
    tr_cast_tile(Wv, WvT, 1024, 2048, t & 15, t >> 4);
  }
}

__global__ __launch_bounds__(256) void transpose_cast(const float* __restrict__ in,
                                                      u16* __restrict__ out,
                                                      int ldin, int ldout) {
  tr_cast_tile(in, out, ldin, ldout, blockIdx.x, blockIdx.y);
}

// ---------------------------------------------------------------------------
// GEMM: C[M,N] = A[M,K] @ BT[N,K]^T. 128x128 tile, m97 LDS pattern, bf16 out.
// R14: 2-phase panel double-buffer — stage 32-wide panel i+1 (4 gl2lds16)
// before computing panel i (8 ds_read + 16 MFMA), ONE barrier per panel.
// Same LDS (32KB), same barrier count as before; loads now overlap compute.
// Keeps R13 bijective XCD remap (768 = 8 x 96).
// ---------------------------------------------------------------------------
__global__ __launch_bounds__(256) void gemm_bt(const u16* __restrict__ A,
                                               const u16* __restrict__ BT,
                                               u16* __restrict__ C,
                                               int M, int N, int K) {
  __shared__ u16 Asl[2][128 * 32];
  __shared__ u16 Bsl[2][128 * 32];
  const int tid = threadIdx.x;
  const int lane = tid & 63, wv = tid >> 6;
  const int lr = lane & 15, qd = lane >> 4;
  const int wr = wv >> 1, wc = wv & 1;
  const int id = blockIdx.y * 48 + blockIdx.x;      // 768 blocks
  const int swz = (id & 7) * 96 + (id >> 3);        // bijective (768 = 8*96)
  const int m0 = (swz / 48) << 7, n0 = (swz % 48) << 7;
  const int srow = lane >> 2, scol = (lane & 3) << 3;
  const u16* Ag = &A[(size_t)(m0 + wv * 32 + srow) * K + scol];
  const u16* Bg = &BT[(size_t)(n0 + wv * 32 + srow) * K + scol];
  const size_t rstr16 = (size_t)16 * K;
  f32x4 acc[4][4] = {};

  auto stageP = [&](int koff, int buf) {
#pragma unroll
    for (int hh = 0; hh < 2; ++hh) {
      gl2lds16(Ag + koff + hh * rstr16, &Asl[buf][wv * 1024 + hh * 512]);
      gl2lds16(Bg + koff + hh * rstr16, &Bsl[buf][wv * 1024 + hh * 512]);
    }
  };
  auto computeP = [&](int p) {
    bf16x8 af[4], bfr[4];
#pragma unroll
    for (int i = 0; i < 4; ++i) {
      af[i]  = *(const bf16x8*)&Asl[p][(wr * 64 + i * 16 + lr) * 32 + qd * 8];
      bfr[i] = *(const bf16x8*)&Bsl[p][(wc * 64 + i * 16 + lr) * 32 + qd * 8];
    }
#pragma unroll
    for (int mi = 0; mi < 4; ++mi)
#pragma unroll
      for (int ni = 0; ni < 4; ++ni)
        acc[mi][ni] = __builtin_amdgcn_mfma_f32_16x16x32_bf16(
            af[mi], bfr[ni], acc[mi][ni], 0, 0, 0);
  };

  const int nsteps = K >> 5;   // 32-wide panels; K=2048 -> 64 (even)
  stageP(0, 0);
#pragma unroll 1
  for (int i = 0; i < nsteps; i += 2) {
    __syncthreads();                       // buf0 staged; all done with buf1
    stageP((i + 1) << 5, 1);
    computeP(0);
    __syncthreads();                       // buf1 staged; all done with buf0
    if (i + 2 < nsteps) stageP((i + 2) << 5, 0);
    computeP(1);
  }
#pragma unroll
  for (int mi = 0; mi < 4; ++mi)
#pragma unroll
    for (int ni = 0; ni < 4; ++ni)
#pragma unroll
      for (int r = 0; r < 4; ++r)
        C[(size_t)(m0 + wr * 64 + mi * 16 + qd * 4 + r) * N +
          n0 + wc * 64 + ni * 16 + lr] = f2bf(acc[mi][ni][r]);
}

// ---------------------------------------------------------------------------
// split-K GEMM (out-proj): f32 += via unsafeAtomicAdd; C pre-zeroed.
// R14: same 2-phase panel dbuf; keeps R13 bijective XCD remap (256 = 8 x 32).
// ---------------------------------------------------------------------------
__global__ __launch_bounds__(256) void gemm_bt_sk(const u16* __restrict__ A,
                                                  const u16* __restrict__ BT,
                                                  float* __restrict__ C,
                                                  int M, int N, int K, int kspan) {
  __shared__ u16 Asl[2][128 * 32];
  __shared__ u16 Bsl[2][128 * 32];
  const int tid = threadIdx.x;
  const int lane = tid & 63, wv = tid >> 6;
  const int lr = lane & 15, qd = lane >> 4;
  const int wr = wv >> 1, wc = wv & 1;
  const int id = blockIdx.y * 16 + blockIdx.x;      // 256 blocks per z
  const int swz = (id & 7) * 32 + (id >> 3);        // bijective (256 = 8*32)
  const int m0 = (swz >> 4) << 7, n0 = (swz & 15) << 7;
  const int kbeg = blockIdx.z * kspan;
  const int srow = lane >> 2, scol = (lane & 3) << 3;
  const u16* Ag = &A[(size_t)(m0 + wv * 32 + srow) * K + kbeg + scol];
  const u16* Bg = &BT[(size_t)(n0 + wv * 32 + srow) * K + kbeg + scol];
  const size_t rstr16 = (size_t)16 * K;
  f32x4 acc[4][4] = {};

  auto stageP = [&](int koff, int buf) {
#pragma unroll
    for (int hh = 0; hh < 2; ++hh) {
      gl2lds16(Ag + koff + hh * rstr16, &Asl[buf][wv * 1024 + hh * 512]);
      gl2lds16(Bg + koff + hh * rstr16, &Bsl[buf][wv * 1024 + hh * 512]);
    }
  };
  auto computeP = [&](int p) {
    bf16x8 af[4], bfr[4];
#pragma unroll
    for (int i = 0; i < 4; ++i) {
      af[i]  = *(const bf16x8*)&Asl[p][(wr * 64 + i * 16 + lr) * 32 + qd * 8];
      bfr[i] = *(const bf16x8*)&Bsl[p][(wc * 64 + i * 16 + lr) * 32 + qd * 8];
    }
#pragma unroll
    for (int mi = 0; mi < 4; ++mi)
#pragma unroll
      for (int ni = 0; ni < 4; ++ni)
        acc[mi][ni] = __builtin_amdgcn_mfma_f32_16x16x32_bf16(
            af[mi], bfr[ni], acc[mi][ni], 0, 0, 0);
  };

  const int nsteps = kspan >> 5;   // kspan=2048 -> 64 (even)
  stageP(0, 0);
#pragma unroll 1
  for (int i = 0; i < nsteps; i += 2) {
    __syncthreads();
    stageP((i + 1) << 5, 1);
    computeP(0);
    __syncthreads();
    if (i + 2 < nsteps) stageP((i + 2) << 5, 0);
    computeP(1);
  }
#pragma unroll
  for (int mi = 0; mi < 4; ++mi)
#pragma unroll
    for (int ni = 0; ni < 4; ++ni)
#pragma unroll
      for (int r = 0; r < 4; ++r)
        unsafeAtomicAdd(&C[(size_t)(m0 + wr * 64 + mi * 16 + qd * 4 + r) * N +
                           n0 + wc * 64 + ni * 16 + lr], acc[mi][ni][r]);
}

// ---------------------------------------------------------------------------
// norm_vt: blocks 0..2047 = fused RMSNorm+RoPE on QKV [2048][6144];
// blocks 2048..2559 = V transpose. Q scaled by log2e/sqrt(128) (exp2 fold).
// ---------------------------------------------------------------------------
__global__ __launch_bounds__(256) void norm_vt(u16* __restrict__ QKV,
                                               u16* __restrict__ VTb,
                                               const float* __restrict__ qw,
                                               const float* __restrict__ kw,
                                               const float* __restrict__ sinb,
                                               const float* __restrict__ cosb) {
  int b = blockIdx.x;
  if (b >= 2048) {
    __shared__ u16 tile[64][66];
    int t = b - 2048;
    const int tx = threadIdx.x;
    const int lr = tx & 31, lc = tx >> 5;
    const int r0 = (t >> 4) << 6, c0 = (t & 15) << 6;
    const u16* in = QKV + 5120;
#pragma unroll
    for (int i = 0; i < 8; ++i) {
      int r = lc + (i << 3);
      unsigned v = *(const unsigned*)&in[(size_t)(r0 + r) * 6144 + c0 + (lr << 1)];
      *(unsigned*)&tile[r][lr << 1] = v;
    }
    __syncthreads();
#pragma unroll
    for (int i = 0; i < 8; ++i) {
      int c = lc + (i << 3);
      unsigned v = (unsigned)tile[lr << 1][c] | ((unsigned)tile[(lr << 1) + 1][c] << 16);
      *(unsigned*)&VTb[(size_t)(c0 + c) * 2048 + r0 + (lr << 1)] = v;
    }
    return;
  }
  const int t = b;
  const int wv = threadIdx.x >> 6, l = threadIdx.x & 63;
  const float sv = sinb[t * 64 + l];
  const float cv = cosb[t * 64 + l];
  const float qscale = 0.12753102543f;  // log2(e)/sqrt(128)
  u16* Q = QKV + (size_t)t * 6144;
  u16* Kb = Q + 4096;
  for (int j = wv; j < 16; j += 4) {
    u16* base = Q + j * 256;
    float x0 = bf2f(base[2 * l]);
    float x1 = bf2f(base[2 * l + 1]);
    float x2 = bf2f(base[128 + 2 * l]);
    float x3 = bf2f(base[129 + 2 * l]);
    float ss = x0 * x0 + x1 * x1 + x2 * x2 + x3 * x3;
#pragma unroll
    for (int m = 1; m < 64; m <<= 1) ss += __shfl_xor(ss, m, 64);
    float rn = rsqrtf(ss * (1.0f / 256.0f) + 1e-6f);
    float w0 = qw[2 * l], w1 = qw[2 * l + 1];
    float w2 = qw[128 + 2 * l], w3 = qw[129 + 2 * l];
    x0 *= rn * w0; x1 *= rn * w1; x2 *= rn * w2; x3 *= rn * w3;
    base[l]       = f2bf((x0 * cv - x1 * sv) * qscale);
    base[64 + l]  = f2bf((x0 * sv + x1 * cv) * qscale);
    base[128 + l] = f2bf((x2 * cv - x3 * sv) * qscale);
    base[192 + l] = f2bf((x2 * sv + x3 * cv) * qscale);
  }
  for (int j = wv; j < 8; j += 4) {
    u16* base = Kb + j * 128;
    float x0 = bf2f(base[2 * l]);
    float x1 = bf2f(base[2 * l + 1]);
    float ss = x0 * x0 + x1 * x1;
#pragma unroll
    for (int m = 1; m < 64; m <<= 1) ss += __shfl_xor(ss, m, 64);
    float rn = rsqrtf(ss * (1.0f / 128.0f) + 1e-6f);
    float w0 = kw[2 * l], w1 = kw[2 * l + 1];
    x0 *= rn * w0; x1 *= rn * w1;
    base[l]      = f2bf(x0 * cv - x1 * sv);
    base[64 + l] = f2bf(x0 * sv + x1 * cv);
  }
}

// ---------------------------------------------------------------------------
// Flash attention, S^T form, NO online max, p=exp2(s). R14 = R12-proven core:
// K AND V staged in LDS (dbuf, one barrier per tile), MFMA32 PV via permlane,
// setprio, single-z (512 blocks = one 2-block/CU residency round), bijective
// XCD grouping wgid%8 == h%8. (R13's V-direct-from-L2 regressed 2x: L2
// latency on the MFMA operand path with no TLP to hide it — reverted.)
// ---------------------------------------------------------------------------
__global__ __launch_bounds__(256, 2) void flash(const u16* __restrict__ QKV,
                                                const u16* __restrict__ VTb,
                                                u16* __restrict__ O,
                                                float* __restrict__ L) {
  __shared__ u16 Ks0[64 * 128];   // [key][d], swizzled
  __shared__ u16 Ks1[64 * 128];
  __shared__ u16 Vs0[128 * 64];   // [d][key], swizzled
  __shared__ u16 Vs1[128 * 64];
  const int tid = threadIdx.x;
  const int wv = tid >> 6, lane = tid & 63;
  const int c = lane & 15, qd = lane >> 4;
  // wgid = r8 + 8*(qx + 16*hh); h = r8 + 8*hh  (bijective; h%8 == wgid%8)
  const int wgid = blockIdx.x;
  const int r8 = wgid & 7, t_ = wgid >> 3;
  const int qx = t_ & 15, hh = t_ >> 4;
  const int h = r8 + (hh << 3);
  const int kv = h >> 2;
  const int qb = (qx << 7) + wv * 32;
  const int cx = c & 7;
  const int krow_off = lane >> 4;
  const int kpb = lane & 15;
  const int vrow_off = lane >> 3;
  const int vpb = lane & 7;
  bf16x8 qf[2][4];
#pragma unroll
  for (int ms = 0; ms < 2; ++ms)
#pragma unroll
    for (int ks = 0; ks < 4; ++ks)
      qf[ms][ks] = *(const bf16x8*)&QKV[(size_t)(qb + ms * 16 + c) * 6144 +
                                        h * 128 + ks * 32 + qd * 8];
  f32x4 o[2][8] = {};
  float lrun[2] = {0.f, 0.f};

  auto stage = [&](int k0, u16* Kd, u16* Vd) {
#pragma unroll
    for (int it = 0; it < 4; ++it) {
      int rbase = (wv * 4 + it) * 4;
      int r = rbase + krow_off;
      int klb = kpb ^ (r & 7);
      gl2lds16(&QKV[(size_t)(k0 + r) * 6144 + 4096 + kv * 128 + klb * 8],
               &Kd[rbase * 128]);
      int dbase = (wv * 4 + it) * 8;
      int d = dbase + vrow_off;
      int vlb = vpb ^ (d & 7);
      gl2lds16(&VTb[(size_t)(kv * 128 + d) * 2048 + k0 + vlb * 8],
               &Vd[dbase * 64]);
    }
  };

  auto compute = [&](const u16* Ks, const u16* Vs) {
    f32x4 s[2][4];
    __builtin_amdgcn_s_setprio(1);
#pragma unroll
    for (int ns = 0; ns < 4; ++ns) {
      f32x4 a0 = {0.f, 0.f, 0.f, 0.f}, a1 = {0.f, 0.f, 0.f, 0.f};
#pragma unroll
      for (int ks = 0; ks < 4; ++ks) {
        bf16x8 kf = *(const bf16x8*)
            &Ks[(ns * 16 + c) * 128 + (((4 * ks + qd) ^ cx) << 3)];
        a0 = __builtin_amdgcn_mfma_f32_16x16x32_bf16(kf, qf[0][ks], a0, 0, 0, 0);
        a1 = __builtin_amdgcn_mfma_f32_16x16x32_bf16(kf, qf[1][ks], a1, 0, 0, 0);
      }
      s[0][ns] = a0; s[1][ns] = a1;
    }
    __builtin_amdgcn_s_setprio(0);
#pragma unroll
    for (int ms = 0; ms < 2; ++ms) {
      float rs = 0.f;
#pragma unroll
      for (int ns = 0; ns < 4; ++ns)
#pragma unroll
        for (int r = 0; r < 4; ++r) {
          float p = EXP2(s[ms][ns][r]);
          s[ms][ns][r] = p; rs += p;
        }
      lrun[ms] += rs;
    }
#ifdef HAVE_PLSWAP
    // PV on 16x16x32: lane must hold 8 consecutive keys of P (B-operand
    // k-group qd). S^T fragments give 4 keys per lane-group; the exchange
    // (b0,b2)=pl16(pl32(p0,p2)), (b1,b3)=pl16(pl32(p1,p3)) produces exactly
    // the dwords [keys 8qd+2d, 8qd+2d+1] per lane.
#pragma unroll
    for (int t2 = 0; t2 < 2; ++t2) {
      bf16x8 pB[2];
#pragma unroll
      for (int ms = 0; ms < 2; ++ms) {
        unsigned p0 = pkbf(s[ms][2 * t2][0],     s[ms][2 * t2][1]);
        unsigned p1 = pkbf(s[ms][2 * t2][2],     s[ms][2 * t2][3]);
        unsigned p2 = pkbf(s[ms][2 * t2 + 1][0], s[ms][2 * t2 + 1][1]);
        unsigned p3 = pkbf(s[ms][2 * t2 + 1][2], s[ms][2 * t2 + 1][3]);
        plswap32(p0, p2); plswap16(p0, p2);  // -> b0, b2
        plswap32(p1, p3); plswap16(p1, p3);  // -> b1, b3
        union { unsigned u[4]; bf16x8 v; } bb;
        bb.u[0] = p0; bb.u[1] = p1; bb.u[2] = p2; bb.u[3] = p3;
        pB[ms] = bb.v;
      }
      __builtin_amdgcn_s_setprio(1);
#pragma unroll
      for (int n8 = 0; n8 < 8; ++n8) {
        bf16x8 vf = *(const bf16x8*)
            &Vs[(n8 * 16 + c) * 64 + (((4 * t2 + qd) ^ cx) << 3)];
        o[0][n8] = __builtin_amdgcn_mfma_f32_16x16x32_bf16(vf, pB[0], o[0][n8], 0, 0, 0);
        o[1][n8] = __builtin_amdgcn_mfma_f32_16x16x32_bf16(vf, pB[1], o[1][n8], 0, 0, 0);
      }
      __builtin_amdgcn_s_setprio(0);
    }
#elif defined(HAVE_MFMA16)
#pragma unroll
    for (int ns = 0; ns < 4; ++ns) {
      s16x4 pb[2];
#pragma unroll
      for (int ms = 0; ms < 2; ++ms) {
        union { unsigned u[2]; s16x4 v; } pu;
        pu.u[0] = pkbf(s[ms][ns][0], s[ms][ns][1]);
        pu.u[1] = pkbf(s[ms][ns][2], s[ms][ns][3]);
        pb[ms] = pu.v;
      }
      const int voff = ((((2 * ns) + (qd >> 1)) ^ cx) << 3) + (qd & 1) * 4;
#pragma unroll
      for (int n8 = 0; n8 < 8; ++n8) {
        s16x4 vf = *(const s16x4*)&Vs[(n8 * 16 + c) * 64 + voff];
        o[0][n8] = MFMA16(vf, pb[0], o[0][n8]);
        o[1][n8] = MFMA16(vf, pb[1], o[1][n8]);
      }
    }
#else
    unsigned pk[2][4][2];
#pragma unroll
    for (int ms = 0; ms < 2; ++ms)
#pragma unroll
      for (int ns = 0; ns < 4; ++ns) {
        pk[ms][ns][0] = pkbf(s[ms][ns][0], s[ms][ns][1]);
        pk[ms][ns][1] = pkbf(s[ms][ns][2], s[ms][ns][3]);
      }
    const bool hi = lane >= 32;
    const int sl0 = ((lane >> 4) & 1) * 32 + c;
    const int sl1 = sl0 + 16;
#pragma unroll
    for (int t2 = 0; t2 < 2; ++t2) {
      union { int i[4]; bf16x8 v; } pb[2];
#pragma unroll
      for (int ms = 0; ms < 2; ++ms)
#pragma unroll
        for (int dw = 0; dw < 4; ++dw) {
          int rg = dw & 1;
          int sl = dw < 2 ? sl0 : sl1;
          int va = __shfl((int)pk[ms][2 * t2][rg], sl, 64);
          int vb = __shfl((int)pk[ms][2 * t2 + 1][rg], sl, 64);
          pb[ms].i[dw] = hi ? vb : va;
        }
#pragma unroll
      for (int n8 = 0; n8 < 8; ++n8) {
        bf16x8 vf = *(const bf16x8*)
            &Vs[(n8 * 16 + c) * 64 + (((4 * t2 + qd) ^ cx) << 3)];
        o[0][n8] = __builtin_amdgcn_mfma_f32_16x16x32_bf16(vf, pb[0].v, o[0][n8], 0, 0, 0);
        o[1][n8] = __builtin_amdgcn_mfma_f32_16x16x32_bf16(vf, pb[1].v, o[1][n8], 0, 0, 0);
      }
    }
#endif
  };

  stage(0, Ks0, Vs0);
#pragma unroll 1
  for (int k0 = 0; k0 < 2048; k0 += 128) {
    __syncthreads();             // drains stage->Ks0/Vs0; all waves done with Ks1/Vs1
    stage(k0 + 64, Ks1, Vs1);    // prefetch next tile; latency hides under compute
    compute(Ks0, Vs0);
    __syncthreads();             // drains stage->Ks1/Vs1; all waves done with Ks0/Vs0
    if (k0 + 128 < 2048) stage(k0 + 128, Ks0, Vs0);
    compute(Ks1, Vs1);
  }
#pragma unroll
  for (int ms = 0; ms < 2; ++ms) {
    lrun[ms] += __shfl_xor(lrun[ms], 16, 64);
    lrun[ms] += __shfl_xor(lrun[ms], 32, 64);
  }
  if (qd == 0) {
    L[(qb + c) * 32 + h] = lrun[0];
    L[(qb + 16 + c) * 32 + h] = lrun[1];
  }
#pragma unroll
  for (int ms = 0; ms < 2; ++ms)
#pragma unroll
    for (int n8 = 0; n8 < 8; ++n8) {
      union { unsigned u[2]; s16x4 v; } w;
      w.u[0] = pkbf(o[ms][n8][0], o[ms][n8][1]);
      w.u[1] = pkbf(o[ms][n8][2], o[ms][n8][3]);
      *(s16x4*)&O[(size_t)(qb + ms * 16 + c) * 4096 + h * 128 + n8 * 16 + qd * 4] = w.v;
    }
}

// ---------------------------------------------------------------------------
// combine: O <- O / L, elementwise over [2048][32][128] (pure normalize).
// ---------------------------------------------------------------------------
__global__ __launch_bounds__(256) void combine(u16* __restrict__ O,
                                               const float* __restrict__ L) {
  int i8 = (blockIdx.x * 256 + threadIdx.x) * 8;
  int q = i8 >> 12, h = (i8 >> 7) & 31;
  float inv = 1.0f / L[q * 32 + h];
  bf16x8 a = *(bf16x8*)&O[i8];
  union { unsigned u[4]; bf16x8 v; } w;
#pragma unroll
  for (int j = 0; j < 4; ++j) {
    float e0 = bf2f((u16)a[2 * j]) * inv;
    float e1 = bf2f((u16)a[2 * j + 1]) * inv;
    w.u[j] = pkbf(e0, e1);
  }
  *(bf16x8*)&O[i8] = w.v;
}

// ---------------------------------------------------------------------------
extern "C" void kernel_launch(void* const* d_in, const int* in_sizes, int n_in,
                              void* d_out, int out_size, void* d_ws, size_t ws_size,
                              hipStream_t stream) {
  const float* x    = (const float*)d_in[0];
  const float* Wq   = (const float*)d_in[1];
  const float* Wk   = (const float*)d_in[2];
  const float* Wv   = (const float*)d_in[3];
  const float* Wo   = (const float*)d_in[4];
  const float* qnw  = (const float*)d_in[5];
  const float* knw  = (const float*)d_in[6];
  const float* sinb = (const float*)d_in[7];
  const float* cosb = (const float*)d_in[8];
  float* out = (float*)d_out;
  char* ws = (char*)d_ws;
  const size_t MB = 1024 * 1024;
  u16* WqkvT = (u16*)(ws + 0 * MB);
  u16* Op0   = (u16*)(ws + 0 * MB);
  float* L0f = (float*)(ws + 16 * MB);
  u16* QKV = (u16*)(ws + 24 * MB);
  u16* WoT = (u16*)(ws + 24 * MB);
  u16* xb  = (u16*)(ws + 48 * MB);
  u16* VTb = (u16*)(ws + 64 * MB);

  prep<<<5120, 256, 0, stream>>>(x, xb, Wq, WqkvT,
                                 Wk, WqkvT + (size_t)4096 * 2048,
                                 Wv, WqkvT + (size_t)5120 * 2048);
  gemm_bt<<<dim3(48, 16), 256, 0, stream>>>(xb, WqkvT, QKV, 2048, 6144, 2048);
  norm_vt<<<2560, 256, 0, stream>>>(QKV, VTb, qnw, knw, sinb, cosb);
  flash<<<512, 256, 0, stream>>>(QKV, VTb, Op0, L0f);
  transpose_cast<<<dim3(32, 64), 256, 0, stream>>>(Wo, WoT, 2048, 4096);
  combine<<<4096, 256, 0, stream>>>(Op0, L0f);
  hipMemsetAsync(out, 0, (size_t)2048 * 2048 * 4, stream);
  gemm_bt_sk<<<dim3(16, 16, 2), 256, 0, stream>>>(Op0, WoT, out, 2048, 2048, 4096, 2048);
  (void)in_sizes; (void)n_in; (void)out_size; (void)ws_size;
}

// Round 8
// 359.276 us; speedup vs baseline: 1.2130x; 1.0853x over previous
//
#include <hip/hip_runtime.h>

typedef unsigned short u16;
typedef __attribute__((ext_vector_type(8))) short bf16x8;
typedef __attribute__((ext_vector_type(4))) short s16x4;
typedef __attribute__((ext_vector_type(4))) float f32x4;

__device__ __forceinline__ float bf2f(u16 u) {
  union { unsigned u; float f; } c; c.u = ((unsigned)u) << 16; return c.f;
}
__device__ __forceinline__ u16 f2bf(float f) {
  union { float f; unsigned u; } c; c.f = f;
  return (u16)((c.u + 0x7fffu + ((c.u >> 16) & 1u)) >> 16);
}
#if __has_builtin(__builtin_amdgcn_cvt_pk_bf16_f32)
__device__ __forceinline__ unsigned pkbf(float a, float b) {
  auto v = __builtin_amdgcn_cvt_pk_bf16_f32(a, b);
  return __builtin_bit_cast(unsigned, v);
}
#else
__device__ __forceinline__ unsigned pkbf(float a, float b) {
  return (unsigned)f2bf(a) | ((unsigned)f2bf(b) << 16);
}
#endif
#if __has_builtin(__builtin_amdgcn_mfma_f32_16x16x16bf16_1k)
#define MFMA16(a, b, c) __builtin_amdgcn_mfma_f32_16x16x16bf16_1k(a, b, c, 0, 0, 0)
#define HAVE_MFMA16 1
#endif
#if __has_builtin(__builtin_amdgcn_permlane16_swap) && \
    __has_builtin(__builtin_amdgcn_permlane32_swap)
#define HAVE_PLSWAP 1
__device__ __forceinline__ void plswap32(unsigned& a, unsigned& b) {
  auto r = __builtin_amdgcn_permlane32_swap(a, b, false, false);
  a = r[0]; b = r[1];
}
__device__ __forceinline__ void plswap16(unsigned& a, unsigned& b) {
  auto r = __builtin_amdgcn_permlane16_swap(a, b, false, false);
  a = r[0]; b = r[1];
}
#endif
// raw exp2 (v_exp_f32); Q pre-scaled by log2e/sqrt(128) so p = e^(qk/sqrt128)
#if __has_builtin(__builtin_amdgcn_exp2f)
#define EXP2(x) __builtin_amdgcn_exp2f(x)
#else
#define EXP2(x) __expf((x) * 0.69314718f)
#endif
__device__ __forceinline__ void gl2lds16(const u16* g, u16* l) {
  __builtin_amdgcn_global_load_lds(
      (const __attribute__((address_space(1))) void*)g,
      (__attribute__((address_space(3))) void*)l, 16, 0, 0);
}

// ---------------------------------------------------------------------------
// transpose_cast tile body: f32 in [.][ldin] -> bf16 out [.][ldout], 64x64.
// ---------------------------------------------------------------------------
__device__ __forceinline__ void tr_cast_tile(const float* __restrict__ in,
                                             u16* __restrict__ out,
                                             int ldin, int ldout, int bx, int by) {
  __shared__ u16 tile[64][66];
  const int tx = threadIdx.x;
  const int lr = tx & 31, lc = tx >> 5;
  const int r0 = by << 6, c0 = bx << 6;
#pragma unroll
  for (int i = 0; i < 8; ++i) {
    int r = lc + (i << 3);
    float2 v = *(const float2*)&in[(size_t)(r0 + r) * ldin + c0 + (lr << 1)];
    *(unsigned*)&tile[r][lr << 1] = pkbf(v.x, v.y);
  }
  __syncthreads();
#pragma unroll
  for (int i = 0; i < 8; ++i) {
    int c = lc + (i << 3);
    unsigned v = (unsigned)tile[lr << 1][c] | ((unsigned)tile[(lr << 1) + 1][c] << 16);
    *(unsigned*)&out[(size_t)(c0 + c) * ldout + r0 + (lr << 1)] = v;
  }
}

// ---------------------------------------------------------------------------
// prep: x cast (blocks 0..2047) + WqT (2048..4095) + WkT (4096..4607) +
// WvT (4608..5119).
// ---------------------------------------------------------------------------
__global__ __launch_bounds__(256) void prep(const float* __restrict__ x,
                                            u16* __restrict__ xb,
                                            const float* __restrict__ Wq,
                                            u16* __restrict__ WqT,
                                            const float* __restrict__ Wk,
                                            u16* __restrict__ WkT,
                                            const float* __restrict__ Wv,
                                            u16* __restrict__ WvT) {
  int b = blockIdx.x;
  if (b < 2048) {
    int i = (b * 256 + threadIdx.x) * 8;
    float4 a = *(const float4*)&x[i];
    float4 c = *(const float4*)&x[i + 4];
    union { unsigned u[4]; bf16x8 v; } w;
    w.u[0] = pkbf(a.x, a.y); w.u[1] = pkbf(a.z, a.w);
    w.u[2] = pkbf(c.x, c.y); w.u[3] = pkbf(c.z, c.w);
    *(bf16x8*)&xb[i] = w.v;
  } else if (b < 4096) {
    int t = b - 2048;
    tr_cast_tile(Wq, WqT, 4096, 2048, t & 63, t >> 6);
  } else if (b < 4608) {
    int t = b - 4096;
    tr_cast_tile(Wk, WkT, 1024, 2048, t & 15, t >> 4);
  } else {
    int t = b - 4608;
    tr_cast_tile(Wv, WvT, 1024, 2048, t & 15, t >> 4);
  }
}

__global__ __launch_bounds__(256) void transpose_cast(const float* __restrict__ in,
                                                      u16* __restrict__ out,
                                                      int ldin, int ldout) {
  tr_cast_tile(in, out, ldin, ldout, blockIdx.x, blockIdx.y);
}

// ---------------------------------------------------------------------------
// BK=64 GEMM: C[M,N] = A[M,K] @ BT[N,K]^T. 128x128 tile, m97 LDS pattern,
// bf16 out. R15 = R13-proven structure (stage 64-K -> drain -> compute; the
// R14 2-phase panel dbuf was neutral-to-negative, matching m99/m100 prior).
// Bijective XCD remap (768 = 8 x 96) kept (measured ~+13us).
// ---------------------------------------------------------------------------
__global__ __launch_bounds__(256) void gemm_bt(const u16* __restrict__ A,
                                               const u16* __restrict__ BT,
                                               u16* __restrict__ C,
                                               int M, int N, int K) {
  __shared__ u16 Asl[2][128 * 32];
  __shared__ u16 Bsl[2][128 * 32];
  const int tid = threadIdx.x;
  const int lane = tid & 63, wv = tid >> 6;
  const int lr = lane & 15, qd = lane >> 4;
  const int wr = wv >> 1, wc = wv & 1;
  const int id = blockIdx.y * 48 + blockIdx.x;      // 768 blocks
  const int swz = (id & 7) * 96 + (id >> 3);        // bijective (768 = 8*96)
  const int m0 = (swz / 48) << 7, n0 = (swz % 48) << 7;
  const int srow = lane >> 2, scol = (lane & 3) << 3;
  const u16* Ag = &A[(size_t)(m0 + wv * 32 + srow) * K + scol];
  const u16* Bg = &BT[(size_t)(n0 + wv * 32 + srow) * K + scol];
  const size_t rstr16 = (size_t)16 * K;
  f32x4 acc[4][4] = {};
  for (int k0 = 0; k0 < K; k0 += 64) {
    __syncthreads();
#pragma unroll
    for (int p = 0; p < 2; ++p) {
#pragma unroll
      for (int hh = 0; hh < 2; ++hh) {
        gl2lds16(Ag + k0 + p * 32 + hh * rstr16, &Asl[p][wv * 1024 + hh * 512]);
        gl2lds16(Bg + k0 + p * 32 + hh * rstr16, &Bsl[p][wv * 1024 + hh * 512]);
      }
    }
    __syncthreads();
#pragma unroll
    for (int p = 0; p < 2; ++p) {
      bf16x8 af[4], bfr[4];
#pragma unroll
      for (int i = 0; i < 4; ++i) {
        af[i]  = *(const bf16x8*)&Asl[p][(wr * 64 + i * 16 + lr) * 32 + qd * 8];
        bfr[i] = *(const bf16x8*)&Bsl[p][(wc * 64 + i * 16 + lr) * 32 + qd * 8];
      }
#pragma unroll
      for (int mi = 0; mi < 4; ++mi)
#pragma unroll
        for (int ni = 0; ni < 4; ++ni)
          acc[mi][ni] = __builtin_amdgcn_mfma_f32_16x16x32_bf16(
              af[mi], bfr[ni], acc[mi][ni], 0, 0, 0);
    }
  }
#pragma unroll
  for (int mi = 0; mi < 4; ++mi)
#pragma unroll
    for (int ni = 0; ni < 4; ++ni)
#pragma unroll
      for (int r = 0; r < 4; ++r)
        C[(size_t)(m0 + wr * 64 + mi * 16 + qd * 4 + r) * N +
          n0 + wc * 64 + ni * 16 + lr] = f2bf(acc[mi][ni][r]);
}

// ---------------------------------------------------------------------------
// BK=64 split-K GEMM (out-proj): f32 += via unsafeAtomicAdd; C pre-zeroed.
// R15 = R13 structure; bijective XCD remap within each z (256 = 8 x 32).
// ---------------------------------------------------------------------------
__global__ __launch_bounds__(256) void gemm_bt_sk(const u16* __restrict__ A,
                                                  const u16* __restrict__ BT,
                                                  float* __restrict__ C,
                                                  int M, int N, int K, int kspan) {
  __shared__ u16 Asl[2][128 * 32];
  __shared__ u16 Bsl[2][128 * 32];
  const int tid = threadIdx.x;
  const int lane = tid & 63, wv = tid >> 6;
  const int lr = lane & 15, qd = lane >> 4;
  const int wr = wv >> 1, wc = wv & 1;
  const int id = blockIdx.y * 16 + blockIdx.x;      // 256 blocks per z
  const int swz = (id & 7) * 32 + (id >> 3);        // bijective (256 = 8*32)
  const int m0 = (swz >> 4) << 7, n0 = (swz & 15) << 7;
  const int kbeg = blockIdx.z * kspan;
  const int srow = lane >> 2, scol = (lane & 3) << 3;
  const u16* Ag = &A[(size_t)(m0 + wv * 32 + srow) * K + kbeg + scol];
  const u16* Bg = &BT[(size_t)(n0 + wv * 32 + srow) * K + kbeg + scol];
  const size_t rstr16 = (size_t)16 * K;
  f32x4 acc[4][4] = {};
  for (int k0 = 0; k0 < kspan; k0 += 64) {
    __syncthreads();
#pragma unroll
    for (int p = 0; p < 2; ++p) {
#pragma unroll
      for (int hh = 0; hh < 2; ++hh) {
        gl2lds16(Ag + k0 + p * 32 + hh * rstr16, &Asl[p][wv * 1024 + hh * 512]);
        gl2lds16(Bg + k0 + p * 32 + hh * rstr16, &Bsl[p][wv * 1024 + hh * 512]);
      }
    }
    __syncthreads();
#pragma unroll
    for (int p = 0; p < 2; ++p) {
      bf16x8 af[4], bfr[4];
#pragma unroll
      for (int i = 0; i < 4; ++i) {
        af[i]  = *(const bf16x8*)&Asl[p][(wr * 64 + i * 16 + lr) * 32 + qd * 8];
        bfr[i] = *(const bf16x8*)&Bsl[p][(wc * 64 + i * 16 + lr) * 32 + qd * 8];
      }
#pragma unroll
      for (int mi = 0; mi < 4; ++mi)
#pragma unroll
        for (int ni = 0; ni < 4; ++ni)
          acc[mi][ni] = __builtin_amdgcn_mfma_f32_16x16x32_bf16(
              af[mi], bfr[ni], acc[mi][ni], 0, 0, 0);
    }
  }
#pragma unroll
  for (int mi = 0; mi < 4; ++mi)
#pragma unroll
    for (int ni = 0; ni < 4; ++ni)
#pragma unroll
      for (int r = 0; r < 4; ++r)
        unsafeAtomicAdd(&C[(size_t)(m0 + wr * 64 + mi * 16 + qd * 4 + r) * N +
                           n0 + wc * 64 + ni * 16 + lr], acc[mi][ni][r]);
}

// ---------------------------------------------------------------------------
// norm_vt: blocks 0..2047 = fused RMSNorm+RoPE on QKV [2048][6144];
// blocks 2048..2559 = V transpose. Q scaled by log2e/sqrt(128) (exp2 fold).
// ---------------------------------------------------------------------------
__global__ __launch_bounds__(256) void norm_vt(u16* __restrict__ QKV,
                                               u16* __restrict__ VTb,
                                               const float* __restrict__ qw,
                                               const float* __restrict__ kw,
                                               const float* __restrict__ sinb,
                                               const float* __restrict__ cosb) {
  int b = blockIdx.x;
  if (b >= 2048) {
    __shared__ u16 tile[64][66];
    int t = b - 2048;
    const int tx = threadIdx.x;
    const int lr = tx & 31, lc = tx >> 5;
    const int r0 = (t >> 4) << 6, c0 = (t & 15) << 6;
    const u16* in = QKV + 5120;
#pragma unroll
    for (int i = 0; i < 8; ++i) {
      int r = lc + (i << 3);
      unsigned v = *(const unsigned*)&in[(size_t)(r0 + r) * 6144 + c0 + (lr << 1)];
      *(unsigned*)&tile[r][lr << 1] = v;
    }
    __syncthreads();
#pragma unroll
    for (int i = 0; i < 8; ++i) {
      int c = lc + (i << 3);
      unsigned v = (unsigned)tile[lr << 1][c] | ((unsigned)tile[(lr << 1) + 1][c] << 16);
      *(unsigned*)&VTb[(size_t)(c0 + c) * 2048 + r0 + (lr << 1)] = v;
    }
    return;
  }
  const int t = b;
  const int wv = threadIdx.x >> 6, l = threadIdx.x & 63;
  const float sv = sinb[t * 64 + l];
  const float cv = cosb[t * 64 + l];
  const float qscale = 0.12753102543f;  // log2(e)/sqrt(128)
  u16* Q = QKV + (size_t)t * 6144;
  u16* Kb = Q + 4096;
  for (int j = wv; j < 16; j += 4) {
    u16* base = Q + j * 256;
    float x0 = bf2f(base[2 * l]);
    float x1 = bf2f(base[2 * l + 1]);
    float x2 = bf2f(base[128 + 2 * l]);
    float x3 = bf2f(base[129 + 2 * l]);
    float ss = x0 * x0 + x1 * x1 + x2 * x2 + x3 * x3;
#pragma unroll
    for (int m = 1; m < 64; m <<= 1) ss += __shfl_xor(ss, m, 64);
    float rn = rsqrtf(ss * (1.0f / 256.0f) + 1e-6f);
    float w0 = qw[2 * l], w1 = qw[2 * l + 1];
    float w2 = qw[128 + 2 * l], w3 = qw[129 + 2 * l];
    x0 *= rn * w0; x1 *= rn * w1; x2 *= rn * w2; x3 *= rn * w3;
    base[l]       = f2bf((x0 * cv - x1 * sv) * qscale);
    base[64 + l]  = f2bf((x0 * sv + x1 * cv) * qscale);
    base[128 + l] = f2bf((x2 * cv - x3 * sv) * qscale);
    base[192 + l] = f2bf((x2 * sv + x3 * cv) * qscale);
  }
  for (int j = wv; j < 8; j += 4) {
    u16* base = Kb + j * 128;
    float x0 = bf2f(base[2 * l]);
    float x1 = bf2f(base[2 * l + 1]);
    float ss = x0 * x0 + x1 * x1;
#pragma unroll
    for (int m = 1; m < 64; m <<= 1) ss += __shfl_xor(ss, m, 64);
    float rn = rsqrtf(ss * (1.0f / 128.0f) + 1e-6f);
    float w0 = kw[2 * l], w1 = kw[2 * l + 1];
    x0 *= rn * w0; x1 *= rn * w1;
    base[l]      = f2bf(x0 * cv - x1 * sv);
    base[64 + l] = f2bf(x0 * sv + x1 * cv);
  }
}

// ---------------------------------------------------------------------------
// Flash attention, S^T form, NO online max, p=exp2(s). R15 = R12 core
// (K+V staged LDS dbuf, one barrier/tile, PLSWAP PV, setprio, single-z,
// bijective XCD grouping) + IN-KERNEL normalization: lrun is the complete
// 2048-key row sum after the qd-reduction (single-z), so O is written
// normalized and the combine pass + L buffer are deleted entirely.
// ---------------------------------------------------------------------------
__global__ __launch_bounds__(256, 2) void flash(const u16* __restrict__ QKV,
                                                const u16* __restrict__ VTb,
                                                u16* __restrict__ O) {
  __shared__ u16 Ks0[64 * 128];   // [key][d], swizzled
  __shared__ u16 Ks1[64 * 128];
  __shared__ u16 Vs0[128 * 64];   // [d][key], swizzled
  __shared__ u16 Vs1[128 * 64];
  const int tid = threadIdx.x;
  const int wv = tid >> 6, lane = tid & 63;
  const int c = lane & 15, qd = lane >> 4;
  // wgid = r8 + 8*(qx + 16*hh); h = r8 + 8*hh  (bijective; h%8 == wgid%8)
  const int wgid = blockIdx.x;
  const int r8 = wgid & 7, t_ = wgid >> 3;
  const int qx = t_ & 15, hh = t_ >> 4;
  const int h = r8 + (hh << 3);
  const int kv = h >> 2;
  const int qb = (qx << 7) + wv * 32;
  const int cx = c & 7;
  const int krow_off = lane >> 4;
  const int kpb = lane & 15;
  const int vrow_off = lane >> 3;
  const int vpb = lane & 7;
  bf16x8 qf[2][4];
#pragma unroll
  for (int ms = 0; ms < 2; ++ms)
#pragma unroll
    for (int ks = 0; ks < 4; ++ks)
      qf[ms][ks] = *(const bf16x8*)&QKV[(size_t)(qb + ms * 16 + c) * 6144 +
                                        h * 128 + ks * 32 + qd * 8];
  f32x4 o[2][8] = {};
  float lrun[2] = {0.f, 0.f};

  auto stage = [&](int k0, u16* Kd, u16* Vd) {
#pragma unroll
    for (int it = 0; it < 4; ++it) {
      int rbase = (wv * 4 + it) * 4;
      int r = rbase + krow_off;
      int klb = kpb ^ (r & 7);
      gl2lds16(&QKV[(size_t)(k0 + r) * 6144 + 4096 + kv * 128 + klb * 8],
               &Kd[rbase * 128]);
      int dbase = (wv * 4 + it) * 8;
      int d = dbase + vrow_off;
      int vlb = vpb ^ (d & 7);
      gl2lds16(&VTb[(size_t)(kv * 128 + d) * 2048 + k0 + vlb * 8],
               &Vd[dbase * 64]);
    }
  };

  auto compute = [&](const u16* Ks, const u16* Vs) {
    f32x4 s[2][4];
    __builtin_amdgcn_s_setprio(1);
#pragma unroll
    for (int ns = 0; ns < 4; ++ns) {
      f32x4 a0 = {0.f, 0.f, 0.f, 0.f}, a1 = {0.f, 0.f, 0.f, 0.f};
#pragma unroll
      for (int ks = 0; ks < 4; ++ks) {
        bf16x8 kf = *(const bf16x8*)
            &Ks[(ns * 16 + c) * 128 + (((4 * ks + qd) ^ cx) << 3)];
        a0 = __builtin_amdgcn_mfma_f32_16x16x32_bf16(kf, qf[0][ks], a0, 0, 0, 0);
        a1 = __builtin_amdgcn_mfma_f32_16x16x32_bf16(kf, qf[1][ks], a1, 0, 0, 0);
      }
      s[0][ns] = a0; s[1][ns] = a1;
    }
    __builtin_amdgcn_s_setprio(0);
#pragma unroll
    for (int ms = 0; ms < 2; ++ms) {
      float rs = 0.f;
#pragma unroll
      for (int ns = 0; ns < 4; ++ns)
#pragma unroll
        for (int r = 0; r < 4; ++r) {
          float p = EXP2(s[ms][ns][r]);
          s[ms][ns][r] = p; rs += p;
        }
      lrun[ms] += rs;
    }
#ifdef HAVE_PLSWAP
    // PV on 16x16x32: lane must hold 8 consecutive keys of P (B-operand
    // k-group qd). S^T fragments give 4 keys per lane-group; the exchange
    // (b0,b2)=pl16(pl32(p0,p2)), (b1,b3)=pl16(pl32(p1,p3)) produces exactly
    // the dwords [keys 8qd+2d, 8qd+2d+1] per lane.
#pragma unroll
    for (int t2 = 0; t2 < 2; ++t2) {
      bf16x8 pB[2];
#pragma unroll
      for (int ms = 0; ms < 2; ++ms) {
        unsigned p0 = pkbf(s[ms][2 * t2][0],     s[ms][2 * t2][1]);
        unsigned p1 = pkbf(s[ms][2 * t2][2],     s[ms][2 * t2][3]);
        unsigned p2 = pkbf(s[ms][2 * t2 + 1][0], s[ms][2 * t2 + 1][1]);
        unsigned p3 = pkbf(s[ms][2 * t2 + 1][2], s[ms][2 * t2 + 1][3]);
        plswap32(p0, p2); plswap16(p0, p2);  // -> b0, b2
        plswap32(p1, p3); plswap16(p1, p3);  // -> b1, b3
        union { unsigned u[4]; bf16x8 v; } bb;
        bb.u[0] = p0; bb.u[1] = p1; bb.u[2] = p2; bb.u[3] = p3;
        pB[ms] = bb.v;
      }
      __builtin_amdgcn_s_setprio(1);
#pragma unroll
      for (int n8 = 0; n8 < 8; ++n8) {
        bf16x8 vf = *(const bf16x8*)
            &Vs[(n8 * 16 + c) * 64 + (((4 * t2 + qd) ^ cx) << 3)];
        o[0][n8] = __builtin_amdgcn_mfma_f32_16x16x32_bf16(vf, pB[0], o[0][n8], 0, 0, 0);
        o[1][n8] = __builtin_amdgcn_mfma_f32_16x16x32_bf16(vf, pB[1], o[1][n8], 0, 0, 0);
      }
      __builtin_amdgcn_s_setprio(0);
    }
#elif defined(HAVE_MFMA16)
#pragma unroll
    for (int ns = 0; ns < 4; ++ns) {
      s16x4 pb[2];
#pragma unroll
      for (int ms = 0; ms < 2; ++ms) {
        union { unsigned u[2]; s16x4 v; } pu;
        pu.u[0] = pkbf(s[ms][ns][0], s[ms][ns][1]);
        pu.u[1] = pkbf(s[ms][ns][2], s[ms][ns][3]);
        pb[ms] = pu.v;
      }
      const int voff = ((((2 * ns) + (qd >> 1)) ^ cx) << 3) + (qd & 1) * 4;
#pragma unroll
      for (int n8 = 0; n8 < 8; ++n8) {
        s16x4 vf = *(const s16x4*)&Vs[(n8 * 16 + c) * 64 + voff];
        o[0][n8] = MFMA16(vf, pb[0], o[0][n8]);
        o[1][n8] = MFMA16(vf, pb[1], o[1][n8]);
      }
    }
#else
    unsigned pk[2][4][2];
#pragma unroll
    for (int ms = 0; ms < 2; ++ms)
#pragma unroll
      for (int ns = 0; ns < 4; ++ns) {
        pk[ms][ns][0] = pkbf(s[ms][ns][0], s[ms][ns][1]);
        pk[ms][ns][1] = pkbf(s[ms][ns][2], s[ms][ns][3]);
      }
    const bool hi = lane >= 32;
    const int sl0 = ((lane >> 4) & 1) * 32 + c;
    const int sl1 = sl0 + 16;
#pragma unroll
    for (int t2 = 0; t2 < 2; ++t2) {
      union { int i[4]; bf16x8 v; } pb[2];
#pragma unroll
      for (int ms = 0; ms < 2; ++ms)
#pragma unroll
        for (int dw = 0; dw < 4; ++dw) {
          int rg = dw & 1;
          int sl = dw < 2 ? sl0 : sl1;
          int va = __shfl((int)pk[ms][2 * t2][rg], sl, 64);
          int vb = __shfl((int)pk[ms][2 * t2 + 1][rg], sl, 64);
          pb[ms].i[dw] = hi ? vb : va;
        }
#pragma unroll
      for (int n8 = 0; n8 < 8; ++n8) {
        bf16x8 vf = *(const bf16x8*)
            &Vs[(n8 * 16 + c) * 64 + (((4 * t2 + qd) ^ cx) << 3)];
        o[0][n8] = __builtin_amdgcn_mfma_f32_16x16x32_bf16(vf, pb[0].v, o[0][n8], 0, 0, 0);
        o[1][n8] = __builtin_amdgcn_mfma_f32_16x16x32_bf16(vf, pb[1].v, o[1][n8], 0, 0, 0);
      }
    }
#endif
  };

  stage(0, Ks0, Vs0);
#pragma unroll 1
  for (int k0 = 0; k0 < 2048; k0 += 128) {
    __syncthreads();             // drains stage->Ks0/Vs0; all waves done with Ks1/Vs1
    stage(k0 + 64, Ks1, Vs1);    // prefetch next tile; latency hides under compute
    compute(Ks0, Vs0);
    __syncthreads();             // drains stage->Ks1/Vs1; all waves done with Ks0/Vs0
    if (k0 + 128 < 2048) stage(k0 + 128, Ks0, Vs0);
    compute(Ks1, Vs1);
  }
#pragma unroll
  for (int ms = 0; ms < 2; ++ms) {
    lrun[ms] += __shfl_xor(lrun[ms], 16, 64);
    lrun[ms] += __shfl_xor(lrun[ms], 32, 64);
  }
  const float inv0 = 1.0f / lrun[0];
  const float inv1 = 1.0f / lrun[1];
#pragma unroll
  for (int ms = 0; ms < 2; ++ms) {
    const float inv = ms ? inv1 : inv0;
#pragma unroll
    for (int n8 = 0; n8 < 8; ++n8) {
      union { unsigned u[2]; s16x4 v; } w;
      w.u[0] = pkbf(o[ms][n8][0] * inv, o[ms][n8][1] * inv);
      w.u[1] = pkbf(o[ms][n8][2] * inv, o[ms][n8][3] * inv);
      *(s16x4*)&O[(size_t)(qb + ms * 16 + c) * 4096 + h * 128 + n8 * 16 + qd * 4] = w.v;
    }
  }
}

// ---------------------------------------------------------------------------
extern "C" void kernel_launch(void* const* d_in, const int* in_sizes, int n_in,
                              void* d_out, int out_size, void* d_ws, size_t ws_size,
                              hipStream_t stream) {
  const float* x    = (const float*)d_in[0];
  const float* Wq   = (const float*)d_in[1];
  const float* Wk   = (const float*)d_in[2];
  const float* Wv   = (const float*)d_in[3];
  const float* Wo   = (const float*)d_in[4];
  const float* qnw  = (const float*)d_in[5];
  const float* knw  = (const float*)d_in[6];
  const float* sinb = (const float*)d_in[7];
  const float* cosb = (const float*)d_in[8];
  float* out = (float*)d_out;
  char* ws = (char*)d_ws;
  const size_t MB = 1024 * 1024;
  u16* WqkvT = (u16*)(ws + 0 * MB);
  u16* Op0   = (u16*)(ws + 0 * MB);
  u16* QKV = (u16*)(ws + 24 * MB);
  u16* WoT = (u16*)(ws + 24 * MB);
  u16* xb  = (u16*)(ws + 48 * MB);
  u16* VTb = (u16*)(ws + 64 * MB);

  prep<<<5120, 256, 0, stream>>>(x, xb, Wq, WqkvT,
                                 Wk, WqkvT + (size_t)4096 * 2048,
                                 Wv, WqkvT + (size_t)5120 * 2048);
  gemm_bt<<<dim3(48, 16), 256, 0, stream>>>(xb, WqkvT, QKV, 2048, 6144, 2048);
  norm_vt<<<2560, 256, 0, stream>>>(QKV, VTb, qnw, knw, sinb, cosb);
  flash<<<512, 256, 0, stream>>>(QKV, VTb, Op0);
  transpose_cast<<<dim3(32, 64), 256, 0, stream>>>(Wo, WoT, 2048, 4096);
  hipMemsetAsync(out, 0, (size_t)2048 * 2048 * 4, stream);
  gemm_bt_sk<<<dim3(16, 16, 2), 256, 0, stream>>>(Op0, WoT, out, 2048, 2048, 4096, 2048);
  (void)in_sizes; (void)n_in; (void)out_size; (void)ws_size;
}